// Round 2
// baseline (3754.440 us; speedup 1.0000x reference)
//
#include <hip/hip_runtime.h>
#include <cstddef>

// Problem constants
constexpr int B_      = 4;
constexpr int L_      = 1024;
constexpr int DM      = 512;    // d_model
constexpr int DS      = 16;     // d_state
constexpr int DI      = 1024;   // d_inner
constexpr int DTR     = 32;     // dt_rank
constexpr int TOK     = B_ * L_;  // 4096 tokens
constexpr int NLAYERS = 2;

// ---- Workspace layout (BYTE offsets). Total = 142,606,336 B (~136 MiB). ----
// XZ : bf16 [4][TOK][2*DI]  (in_proj out; z-half live until combine; yo overlays after)
// XC : bf16 [8][TOK][DI]    (conv out; scan writes y in-place; combine writes ycomb in-place)
// PR : f32  [8][TOK][64]    (xproj out: dt_r | B | C)
constexpr size_t XZB = 0;
constexpr size_t XCB = (size_t)4 * TOK * 2 * DI * 2;          // 67,108,864
constexpr size_t PRB = XCB + (size_t)8 * TOK * DI * 2;        // 134,217,728
// yo f32 [4][TOK][DM] = 33,554,432 B overlays XZ region (xz dead after combine).

__device__ __forceinline__ float silu_f(float x) { return x / (1.f + __expf(-x)); }

__device__ __forceinline__ float bf2f(unsigned short u) {
    union { unsigned u; float f; } v; v.u = ((unsigned)u) << 16; return v.f;
}
__device__ __forceinline__ unsigned short f2bf(float f) {
    union { float f; unsigned u; } v; v.f = f;
    unsigned r = v.u + 0x7FFFu + ((v.u >> 16) & 1u);
    return (unsigned short)(r >> 16);
}

// ---------------- Generic tiled GEMM: C[M,N] = A[M,K] @ W[N,K]^T ----------------
// 64x64 tile, BK=16, 256 threads, 4x4 micro-tile. A: f32 or bf16. C: f32 or bf16.
template<int N, int K, typename TA, typename TC>
__device__ __forceinline__ void gemm_tile_nt(const TA* __restrict__ A,
                                             const float* __restrict__ W,
                                             TC* __restrict__ C)
{
    __shared__ float As[16][68];
    __shared__ float Ws[16][68];
    const int tid = threadIdx.x;
    const int tx = tid & 15, ty = tid >> 4;
    const int row0 = blockIdx.y * 64, col0 = blockIdx.x * 64;
    const int lr = tid >> 2;            // 0..63
    const int lk = (tid & 3) << 2;      // 0,4,8,12
    const TA*    Ap = A + (size_t)(row0 + lr) * K + lk;
    const float* Wp = W + (size_t)(col0 + lr) * K + lk;
    float acc[4][4] = {};
    for (int k0 = 0; k0 < K; k0 += 16) {
        float a0, a1, a2, a3;
        if constexpr (sizeof(TA) == 4) {
            float4 av = *(const float4*)(Ap + k0);
            a0 = av.x; a1 = av.y; a2 = av.z; a3 = av.w;
        } else {
            ushort4 av = *(const ushort4*)(Ap + k0);
            a0 = bf2f(av.x); a1 = bf2f(av.y); a2 = bf2f(av.z); a3 = bf2f(av.w);
        }
        float4 wv = *(const float4*)(Wp + k0);
        As[lk + 0][lr] = a0; As[lk + 1][lr] = a1;
        As[lk + 2][lr] = a2; As[lk + 3][lr] = a3;
        Ws[lk + 0][lr] = wv.x; Ws[lk + 1][lr] = wv.y;
        Ws[lk + 2][lr] = wv.z; Ws[lk + 3][lr] = wv.w;
        __syncthreads();
#pragma unroll
        for (int k = 0; k < 16; ++k) {
            float b0 = As[k][ty * 4 + 0], b1 = As[k][ty * 4 + 1];
            float b2 = As[k][ty * 4 + 2], b3 = As[k][ty * 4 + 3];
            float w0 = Ws[k][tx * 4 + 0], w1 = Ws[k][tx * 4 + 1];
            float w2 = Ws[k][tx * 4 + 2], w3 = Ws[k][tx * 4 + 3];
            acc[0][0] += b0 * w0; acc[0][1] += b0 * w1; acc[0][2] += b0 * w2; acc[0][3] += b0 * w3;
            acc[1][0] += b1 * w0; acc[1][1] += b1 * w1; acc[1][2] += b1 * w2; acc[1][3] += b1 * w3;
            acc[2][0] += b2 * w0; acc[2][1] += b2 * w1; acc[2][2] += b2 * w2; acc[2][3] += b2 * w3;
            acc[3][0] += b3 * w0; acc[3][1] += b3 * w1; acc[3][2] += b3 * w2; acc[3][3] += b3 * w3;
        }
        __syncthreads();
    }
#pragma unroll
    for (int i = 0; i < 4; ++i) {
        size_t off = (size_t)(row0 + ty * 4 + i) * N + col0 + tx * 4;
        if constexpr (sizeof(TC) == 4) {
            *(float4*)(C + off) = make_float4(acc[i][0], acc[i][1], acc[i][2], acc[i][3]);
        } else {
            ushort4 o;
            o.x = f2bf(acc[i][0]); o.y = f2bf(acc[i][1]);
            o.z = f2bf(acc[i][2]); o.w = f2bf(acc[i][3]);
            *(ushort4*)(C + off) = o;
        }
    }
}

// ---------------- in_proj: xz[g] = src_g @ in_proj_w[li]^T (bf16 out) ----------------
// grid (32, 64, 4), block 256
__global__ __launch_bounds__(256)
void k_inproj(const float* __restrict__ pa, const float* __restrict__ pt,
              const float* __restrict__ pv, const float* __restrict__ w_all,
              unsigned short* __restrict__ xz, int layer)
{
    int g = blockIdx.z;
    const float* A = (g == 0) ? pa : (g == 2) ? pv : pt;
    int li = 2 * layer + (g >> 1);
    gemm_tile_nt<2 * DI, DM, float, unsigned short>(
        A, w_all + (size_t)li * (2 * DI) * DM, xz + (size_t)g * TOK * (2 * DI));
}

// ---------------- causal/anticausal depthwise conv + SiLU (bf16 in/out) ----------------
// grid (4, 4096, 8), block 256
__global__ __launch_bounds__(256)
void k_conv(const unsigned short* __restrict__ xz, const float* __restrict__ cw,
            const float* __restrict__ cb, unsigned short* __restrict__ xc, int layer)
{
    int d  = blockIdx.x * 256 + threadIdx.x;
    int mt = blockIdx.y;             // global token = b*1024 + t
    int gd = blockIdx.z;
    int g = gd >> 1, dir = gd & 1;
    int li = 2 * layer + (g >> 1);
    int wi = (li * 2 + dir) * DI + d;
    const float* wp = cw + (size_t)wi * 4;
    float w0 = wp[0], w1 = wp[1], w2 = wp[2], w3 = wp[3];
    float s = cb[wi];
    int b = mt >> 10, tt = mt & 1023;
    const unsigned short* xcol = xz + ((size_t)g * TOK + (size_t)(b << 10)) * (2 * DI) + d;
    if (dir == 0) {
        if (tt >= 3) s += w0 * bf2f(xcol[(size_t)(tt - 3) * (2 * DI)]);
        if (tt >= 2) s += w1 * bf2f(xcol[(size_t)(tt - 2) * (2 * DI)]);
        if (tt >= 1) s += w2 * bf2f(xcol[(size_t)(tt - 1) * (2 * DI)]);
        s += w3 * bf2f(xcol[(size_t)tt * (2 * DI)]);
    } else {
        s += w3 * bf2f(xcol[(size_t)tt * (2 * DI)]);
        if (tt + 1 < L_) s += w2 * bf2f(xcol[(size_t)(tt + 1) * (2 * DI)]);
        if (tt + 2 < L_) s += w1 * bf2f(xcol[(size_t)(tt + 2) * (2 * DI)]);
        if (tt + 3 < L_) s += w0 * bf2f(xcol[(size_t)(tt + 3) * (2 * DI)]);
    }
    xc[((size_t)gd * TOK + mt) * DI + d] = f2bf(silu_f(s));
}

// ---------------- xproj: proj[gd] = xc[gd] @ xproj_w[li,dir]^T (f32 out) ----------------
// grid (1, 64, 8), block 256
__global__ __launch_bounds__(256)
void k_xproj(const unsigned short* __restrict__ xc, const float* __restrict__ xpw,
             float* __restrict__ proj, int layer)
{
    int gd = blockIdx.z;
    int dir = gd & 1;
    int li = 2 * layer + (gd >> 2);
    gemm_tile_nt<64, DI, unsigned short, float>(
        xc + (size_t)gd * TOK * DI,
        xpw + (size_t)(li * 2 + dir) * 64 * DI,
        proj + (size_t)gd * TOK * 64);
}

// ---------------- selective scan, dtproj fused, y written IN PLACE over xc ----------------
// grid (16, 4, 8), block 64. One thread per channel; 16 states + 32 dt-weights in regs.
__global__ __launch_bounds__(64)
void k_scan(unsigned short* __restrict__ xc, const float* __restrict__ proj,
            const float* __restrict__ dpw, const float* __restrict__ dpb,
            const float* __restrict__ A_log, const float* __restrict__ Dskip, int layer)
{
    int gd = blockIdx.z;
    int g = gd >> 1, dir = gd & 1;
    int li = 2 * layer + (g >> 1);
    int d = blockIdx.x * 64 + threadIdx.x;
    int b = blockIdx.y;
    int wl = (li * 2 + dir) * DI + d;

    float w[DTR];
    const float* wp = dpw + (size_t)wl * DTR;
#pragma unroll
    for (int k = 0; k < DTR; ++k) w[k] = wp[k];
    float bias = dpb[wl];
    float An[DS];
    const float* Ap = A_log + (size_t)wl * DS;
#pragma unroll
    for (int n = 0; n < DS; ++n) An[n] = -__expf(Ap[n]);
    float Dk = Dskip[wl];
    float h[DS];
#pragma unroll
    for (int n = 0; n < DS; ++n) h[n] = 0.f;

    const size_t base_x = ((size_t)gd * TOK + (size_t)b * L_) * DI + d;
    const float* prbase = proj + ((size_t)gd * TOK + (size_t)b * L_) * 64;

    int t = dir ? (L_ - 1) : 0;
    const int step = dir ? -1 : 1;
    float uv = bf2f(xc[base_x + (size_t)t * DI]);
    for (int s = 0; s < L_; ++s) {
        int tn = t + step;
        float un = 0.f;
        if (s + 1 < L_) un = bf2f(xc[base_x + (size_t)tn * DI]);   // read tn BEFORE write t
        const float* pr = prbase + (size_t)t * 64;                 // wave-uniform row
        float dts = bias;
#pragma unroll
        for (int k = 0; k < DTR; ++k) dts += w[k] * pr[k];
        float dt = fmaxf(dts, 0.f) + log1pf(__expf(-fabsf(dts)));  // softplus
        float du = dt * uv;
        float acc = 0.f;
#pragma unroll
        for (int n = 0; n < DS; ++n) {
            float dA = __expf(dt * An[n]);
            h[n] = dA * h[n] + du * pr[32 + n];
            acc += h[n] * pr[48 + n];
        }
        xc[base_x + (size_t)t * DI] = f2bf(acc + uv * Dk);         // y in place
        t = tn; uv = un;
    }
}

// ---------------- combine: ycomb = (yf+yb)*silu(z), in place over y_fwd slot ----------------
// grid (4096, 4), block 256; ushort4 per thread
__global__ __launch_bounds__(256)
void k_combine(unsigned short* __restrict__ xcbuf, const unsigned short* __restrict__ xz)
{
    int g = blockIdx.y;
    size_t idx = ((size_t)blockIdx.x * 256 + threadIdx.x) * 4;   // m*DI + d
    size_t m = idx >> 10, d = idx & 1023;
    unsigned short* yf_p = xcbuf + (size_t)(2 * g) * TOK * DI + idx;
    const unsigned short* yb_p = xcbuf + (size_t)(2 * g + 1) * TOK * DI + idx;
    const unsigned short* z_p  = xz + ((size_t)g * TOK + m) * (2 * DI) + DI + d;
    ushort4 yf = *(const ushort4*)yf_p;
    ushort4 yb = *(const ushort4*)yb_p;
    ushort4 zz = *(const ushort4*)z_p;
    ushort4 o;
    o.x = f2bf((bf2f(yf.x) + bf2f(yb.x)) * silu_f(bf2f(zz.x)));
    o.y = f2bf((bf2f(yf.y) + bf2f(yb.y)) * silu_f(bf2f(zz.y)));
    o.z = f2bf((bf2f(yf.z) + bf2f(yb.z)) * silu_f(bf2f(zz.z)));
    o.w = f2bf((bf2f(yf.w) + bf2f(yb.w)) * silu_f(bf2f(zz.w)));
    *(ushort4*)yf_p = o;
}

// ---------------- out_proj: yo[g] = ycomb[g] @ out_proj_w[li]^T (f32 out) ----------------
// grid (8, 64, 4), block 256
__global__ __launch_bounds__(256)
void k_outproj(const unsigned short* __restrict__ xcbuf, const float* __restrict__ opw,
               float* __restrict__ yo, int layer)
{
    int g = blockIdx.z;
    int li = 2 * layer + (g >> 1);
    gemm_tile_nt<DM, DI, unsigned short, float>(
        xcbuf + (size_t)(2 * g) * TOK * DI,
        opw + (size_t)li * DM * DI,
        yo + (size_t)g * TOK * DM);
}

// ---------------- LayerNorm + residual + t-average ----------------
__device__ __forceinline__ void blk_red2(float& a, float& b, float* red)
{
#pragma unroll
    for (int o = 32; o; o >>= 1) {
        a += __shfl_down(a, o);
        b += __shfl_down(b, o);
    }
    int lane = threadIdx.x & 63, wid = threadIdx.x >> 6;
    if (lane == 0) { red[wid] = a; red[4 + wid] = b; }
    __syncthreads();
    a = red[0] + red[1] + red[2] + red[3];
    b = red[4] + red[5] + red[6] + red[7];
    __syncthreads();
}

// grid (4096), block 256 (each thread covers cols tid, tid+256)
__global__ __launch_bounds__(256)
void k_ln(const float* __restrict__ yo, const float* __restrict__ lnw,
          const float* __restrict__ lnb, const float* __restrict__ resA,
          const float* __restrict__ resT, const float* __restrict__ resV,
          float* __restrict__ outA, float* __restrict__ outT,
          float* __restrict__ outV, int layer)
{
    int tok = blockIdx.x, tid = threadIdx.x;
    __shared__ float red[8];
    float t1a = 0.f, t1b = 0.f;
#pragma unroll
    for (int s = 0; s < 4; ++s) {
        const float* p = yo + ((size_t)s * TOK + tok) * DM;
        float x0 = p[tid], x1 = p[tid + 256];
        float sm = x0 + x1, sq = x0 * x0 + x1 * x1;
        blk_red2(sm, sq, red);
        float mean = sm * (1.f / 512.f);
        float var  = sq * (1.f / 512.f) - mean * mean;
        float rstd = rsqrtf(var + 1e-6f);
        int li = 2 * layer + (s >> 1);
        int half = s & 1;
        const float* wv = lnw + (size_t)(li * 2 + half) * DM;
        const float* bv = lnb + (size_t)(li * 2 + half) * DM;
        float v0 = (x0 - mean) * rstd * wv[tid] + bv[tid];
        float v1 = (x1 - mean) * rstd * wv[tid + 256] + bv[tid + 256];
        size_t o0 = (size_t)tok * DM + tid, o1 = o0 + 256;
        if (s == 0) {
            outA[o0] = resA[o0] + v0;
            outA[o1] = resA[o1] + v1;
        } else if (s == 1) {
            t1a = v0; t1b = v1;
        } else if (s == 2) {
            outV[o0] = resV[o0] + v0;
            outV[o1] = resV[o1] + v1;
        } else {
            outT[o0] = resT[o0] + 0.5f * (t1a + v0);
            outT[o1] = resT[o1] + 0.5f * (t1b + v1);
        }
    }
}

extern "C" void kernel_launch(void* const* d_in, const int* in_sizes, int n_in,
                              void* d_out, int out_size, void* d_ws, size_t ws_size,
                              hipStream_t stream)
{
    (void)in_sizes; (void)n_in; (void)out_size; (void)ws_size;
    const float* a_x       = (const float*)d_in[0];
    const float* v_x       = (const float*)d_in[1];
    const float* t_x       = (const float*)d_in[2];
    const float* in_proj_w = (const float*)d_in[3];
    const float* conv_w    = (const float*)d_in[4];
    const float* conv_b    = (const float*)d_in[5];
    const float* xproj_w   = (const float*)d_in[6];
    const float* dtproj_w  = (const float*)d_in[7];
    const float* dtproj_b  = (const float*)d_in[8];
    const float* A_log     = (const float*)d_in[9];
    const float* Dskip     = (const float*)d_in[10];
    const float* out_proj_w= (const float*)d_in[11];
    const float* ln_w      = (const float*)d_in[12];
    const float* ln_b      = (const float*)d_in[13];

    char* wsb = (char*)d_ws;
    unsigned short* xz   = (unsigned short*)(wsb + XZB);
    unsigned short* xc   = (unsigned short*)(wsb + XCB);
    float*          proj = (float*)(wsb + PRB);
    float*          yo   = (float*)(wsb + XZB);   // overlays xz (dead after combine)

    float* out   = (float*)d_out;
    float* slotA = out;
    float* slotV = out + (size_t)TOK * DM;
    float* slotT = out + (size_t)2 * TOK * DM;

    for (int layer = 0; layer < NLAYERS; ++layer) {
        const float* sa = layer ? slotA : a_x;
        const float* st = layer ? slotT : t_x;
        const float* sv = layer ? slotV : v_x;

        k_inproj <<<dim3(32, 64, 4),   256, 0, stream>>>(sa, st, sv, in_proj_w, xz, layer);
        k_conv   <<<dim3(4, 4096, 8),  256, 0, stream>>>(xz, conv_w, conv_b, xc, layer);
        k_xproj  <<<dim3(1, 64, 8),    256, 0, stream>>>(xc, xproj_w, proj, layer);
        k_scan   <<<dim3(16, 4, 8),    64,  0, stream>>>(xc, proj, dtproj_w, dtproj_b,
                                                         A_log, Dskip, layer);
        k_combine<<<dim3(4096, 4),     256, 0, stream>>>(xc, xz);
        k_outproj<<<dim3(8, 64, 4),    256, 0, stream>>>(xc, out_proj_w, yo, layer);
        k_ln     <<<dim3(4096),        256, 0, stream>>>(yo, ln_w, ln_b, sa, st, sv,
                                                         slotA, slotT, slotV, layer);
    }
}

// Round 3
// 2606.800 us; speedup vs baseline: 1.4402x; 1.4402x over previous
//
#include <hip/hip_runtime.h>
#include <cstddef>

// Problem constants
constexpr int B_      = 4;
constexpr int L_      = 1024;
constexpr int DM      = 512;    // d_model
constexpr int DS      = 16;     // d_state
constexpr int DI      = 1024;   // d_inner
constexpr int DTR     = 32;     // dt_rank
constexpr int TOK     = B_ * L_;  // 4096 tokens
constexpr int NLAYERS = 2;

// ---- Workspace layout (BYTE offsets). Base = 136 MiB; +64 MiB dt buffer if ws allows. ----
// XZ : bf16 [4][TOK][2*DI]  (in_proj out; z-half live until combine; yo overlays after)
// XC : bf16 [8][TOK][DI]    (conv out; scan writes y in-place; combine writes ycomb in-place)
// PR : f32  [8][TOK][64]    (xproj out: dt_r | B | C)
// DT : bf16 [8][TOK][DI]    (optional precomputed softplus(dtproj))
constexpr size_t XZB = 0;
constexpr size_t XCB = (size_t)4 * TOK * 2 * DI * 2;          //  67,108,864
constexpr size_t PRB = XCB + (size_t)8 * TOK * DI * 2;        // 134,217,728
constexpr size_t DTB = PRB + (size_t)8 * TOK * 64 * 4;        // 142,606,336
constexpr size_t WS_NEED_PRE = DTB + (size_t)8 * TOK * DI * 2; // 209,715,200

__device__ __forceinline__ float silu_f(float x) { return x / (1.f + __expf(-x)); }

__device__ __forceinline__ float bf2f(unsigned short u) {
    union { unsigned u; float f; } v; v.u = ((unsigned)u) << 16; return v.f;
}
__device__ __forceinline__ unsigned short f2bf(float f) {
    union { float f; unsigned u; } v; v.f = f;
    unsigned r = v.u + 0x7FFFu + ((v.u >> 16) & 1u);
    return (unsigned short)(r >> 16);
}

// ---------------- Generic tiled GEMM: C[M,N] = A[M,K] @ W[N,K]^T ----------------
// 64x64 tile, BK=16, 256 threads, 4x4 micro-tile. A: f32 or bf16. C: f32 or bf16.
template<int N, int K, typename TA, typename TC>
__device__ __forceinline__ void gemm_tile_nt(const TA* __restrict__ A,
                                             const float* __restrict__ W,
                                             TC* __restrict__ C)
{
    __shared__ float As[16][68];
    __shared__ float Ws[16][68];
    const int tid = threadIdx.x;
    const int tx = tid & 15, ty = tid >> 4;
    const int row0 = blockIdx.y * 64, col0 = blockIdx.x * 64;
    const int lr = tid >> 2;            // 0..63
    const int lk = (tid & 3) << 2;      // 0,4,8,12
    const TA*    Ap = A + (size_t)(row0 + lr) * K + lk;
    const float* Wp = W + (size_t)(col0 + lr) * K + lk;
    float acc[4][4] = {};
    for (int k0 = 0; k0 < K; k0 += 16) {
        float a0, a1, a2, a3;
        if constexpr (sizeof(TA) == 4) {
            float4 av = *(const float4*)(Ap + k0);
            a0 = av.x; a1 = av.y; a2 = av.z; a3 = av.w;
        } else {
            ushort4 av = *(const ushort4*)(Ap + k0);
            a0 = bf2f(av.x); a1 = bf2f(av.y); a2 = bf2f(av.z); a3 = bf2f(av.w);
        }
        float4 wv = *(const float4*)(Wp + k0);
        As[lk + 0][lr] = a0; As[lk + 1][lr] = a1;
        As[lk + 2][lr] = a2; As[lk + 3][lr] = a3;
        Ws[lk + 0][lr] = wv.x; Ws[lk + 1][lr] = wv.y;
        Ws[lk + 2][lr] = wv.z; Ws[lk + 3][lr] = wv.w;
        __syncthreads();
#pragma unroll
        for (int k = 0; k < 16; ++k) {
            float b0 = As[k][ty * 4 + 0], b1 = As[k][ty * 4 + 1];
            float b2 = As[k][ty * 4 + 2], b3 = As[k][ty * 4 + 3];
            float w0 = Ws[k][tx * 4 + 0], w1 = Ws[k][tx * 4 + 1];
            float w2 = Ws[k][tx * 4 + 2], w3 = Ws[k][tx * 4 + 3];
            acc[0][0] += b0 * w0; acc[0][1] += b0 * w1; acc[0][2] += b0 * w2; acc[0][3] += b0 * w3;
            acc[1][0] += b1 * w0; acc[1][1] += b1 * w1; acc[1][2] += b1 * w2; acc[1][3] += b1 * w3;
            acc[2][0] += b2 * w0; acc[2][1] += b2 * w1; acc[2][2] += b2 * w2; acc[2][3] += b2 * w3;
            acc[3][0] += b3 * w0; acc[3][1] += b3 * w1; acc[3][2] += b3 * w2; acc[3][3] += b3 * w3;
        }
        __syncthreads();
    }
#pragma unroll
    for (int i = 0; i < 4; ++i) {
        size_t off = (size_t)(row0 + ty * 4 + i) * N + col0 + tx * 4;
        if constexpr (sizeof(TC) == 4) {
            *(float4*)(C + off) = make_float4(acc[i][0], acc[i][1], acc[i][2], acc[i][3]);
        } else {
            ushort4 o;
            o.x = f2bf(acc[i][0]); o.y = f2bf(acc[i][1]);
            o.z = f2bf(acc[i][2]); o.w = f2bf(acc[i][3]);
            *(ushort4*)(C + off) = o;
        }
    }
}

// ---------------- in_proj: xz[g] = src_g @ in_proj_w[li]^T (bf16 out) ----------------
__global__ __launch_bounds__(256)
void k_inproj(const float* __restrict__ pa, const float* __restrict__ pt,
              const float* __restrict__ pv, const float* __restrict__ w_all,
              unsigned short* __restrict__ xz, int layer)
{
    int g = blockIdx.z;
    const float* A = (g == 0) ? pa : (g == 2) ? pv : pt;
    int li = 2 * layer + (g >> 1);
    gemm_tile_nt<2 * DI, DM, float, unsigned short>(
        A, w_all + (size_t)li * (2 * DI) * DM, xz + (size_t)g * TOK * (2 * DI));
}

// ---------------- causal/anticausal depthwise conv + SiLU (bf16 in/out) ----------------
__global__ __launch_bounds__(256)
void k_conv(const unsigned short* __restrict__ xz, const float* __restrict__ cw,
            const float* __restrict__ cb, unsigned short* __restrict__ xc, int layer)
{
    int d  = blockIdx.x * 256 + threadIdx.x;
    int mt = blockIdx.y;             // global token = b*1024 + t
    int gd = blockIdx.z;
    int g = gd >> 1, dir = gd & 1;
    int li = 2 * layer + (g >> 1);
    int wi = (li * 2 + dir) * DI + d;
    const float* wp = cw + (size_t)wi * 4;
    float w0 = wp[0], w1 = wp[1], w2 = wp[2], w3 = wp[3];
    float s = cb[wi];
    int b = mt >> 10, tt = mt & 1023;
    const unsigned short* xcol = xz + ((size_t)g * TOK + (size_t)(b << 10)) * (2 * DI) + d;
    if (dir == 0) {
        if (tt >= 3) s += w0 * bf2f(xcol[(size_t)(tt - 3) * (2 * DI)]);
        if (tt >= 2) s += w1 * bf2f(xcol[(size_t)(tt - 2) * (2 * DI)]);
        if (tt >= 1) s += w2 * bf2f(xcol[(size_t)(tt - 1) * (2 * DI)]);
        s += w3 * bf2f(xcol[(size_t)tt * (2 * DI)]);
    } else {
        s += w3 * bf2f(xcol[(size_t)tt * (2 * DI)]);
        if (tt + 1 < L_) s += w2 * bf2f(xcol[(size_t)(tt + 1) * (2 * DI)]);
        if (tt + 2 < L_) s += w1 * bf2f(xcol[(size_t)(tt + 2) * (2 * DI)]);
        if (tt + 3 < L_) s += w0 * bf2f(xcol[(size_t)(tt + 3) * (2 * DI)]);
    }
    xc[((size_t)gd * TOK + mt) * DI + d] = f2bf(silu_f(s));
}

// ---------------- xproj: proj[gd] = xc[gd] @ xproj_w[li,dir]^T (f32 out) ----------------
__global__ __launch_bounds__(256)
void k_xproj(const unsigned short* __restrict__ xc, const float* __restrict__ xpw,
             float* __restrict__ proj, int layer)
{
    int gd = blockIdx.z;
    int dir = gd & 1;
    int li = 2 * layer + (gd >> 2);
    gemm_tile_nt<64, DI, unsigned short, float>(
        xc + (size_t)gd * TOK * DI,
        xpw + (size_t)(li * 2 + dir) * 64 * DI,
        proj + (size_t)gd * TOK * 64);
}

// ---------------- dt precompute: dt = softplus(proj[:, :32] @ dpw^T + dpb), bf16 out ----
// grid (DI/256=4, TOK/64=64, 8), block 256
__global__ __launch_bounds__(256)
void k_dtgemm(const float* __restrict__ proj, const float* __restrict__ dpw,
              const float* __restrict__ dpb, unsigned short* __restrict__ dt, int layer)
{
    int gd = blockIdx.z, g = gd >> 1, dir = gd & 1;
    int li = 2 * layer + (g >> 1);
    int d = blockIdx.x * 256 + threadIdx.x;
    int t0 = blockIdx.y * 64;
    __shared__ float ps[64][32];
    const float* pb = proj + ((size_t)gd * TOK + t0) * 64;
    {
        int f0 = threadIdx.x;            // 0..255
        int row = f0 >> 3, c4 = f0 & 7;
        *(float4*)&ps[row][c4 * 4] = *(const float4*)(pb + (size_t)row * 64 + c4 * 4);
        int f1 = f0 + 256;               // 256..511
        row = f1 >> 3; c4 = f1 & 7;
        *(float4*)&ps[row][c4 * 4] = *(const float4*)(pb + (size_t)row * 64 + c4 * 4);
    }
    __syncthreads();
    const float* wp = dpw + ((size_t)(li * 2 + dir) * DI + d) * DTR;
    float w[DTR];
#pragma unroll
    for (int k = 0; k < DTR; ++k) w[k] = wp[k];
    float bias = dpb[(size_t)(li * 2 + dir) * DI + d];
    for (int t = 0; t < 64; ++t) {
        float s = bias;
#pragma unroll
        for (int k = 0; k < DTR; ++k) s += w[k] * ps[t][k];
        float sp = fmaxf(s, 0.f) + log1pf(__expf(-fabsf(s)));
        dt[((size_t)gd * TOK + t0 + t) * DI + d] = f2bf(sp);
    }
}

// ---------------- selective scan, chunked LDS staging, y in place over xc ----------------
// grid (16, 4, 8), block 64 (one wave). PRE_DT: dt from precomputed buffer.
template<bool PRE_DT>
__global__ __launch_bounds__(64)
void k_scan2(unsigned short* __restrict__ xc, const float* __restrict__ proj,
             const unsigned short* __restrict__ dtb,
             const float* __restrict__ dpw, const float* __restrict__ dpb,
             const float* __restrict__ A_log, const float* __restrict__ Dskip, int layer)
{
    constexpr int PRF = PRE_DT ? 32 : 64;   // floats staged per proj row
    __shared__ float prs[64 * PRF];
    __shared__ unsigned short xcs[64 * 64];
    __shared__ unsigned short dts[PRE_DT ? 64 * 64 : 64];

    const int lane = threadIdx.x;
    const int gd = blockIdx.z, g = gd >> 1, dir = gd & 1;
    const int li = 2 * layer + (g >> 1);
    const int b = blockIdx.y;
    const int ch0 = blockIdx.x * 64;
    const int wl = (li * 2 + dir) * DI + ch0 + lane;

    float An[DS];
    const float* Ap = A_log + (size_t)wl * DS;
#pragma unroll
    for (int n = 0; n < DS; ++n) An[n] = -__expf(Ap[n]);
    const float Dk = Dskip[wl];
    float w[PRE_DT ? 1 : DTR];
    float bias = 0.f;
    if constexpr (!PRE_DT) {
        const float* wp = dpw + (size_t)wl * DTR;
#pragma unroll
        for (int k = 0; k < DTR; ++k) w[k] = wp[k];
        bias = dpb[wl];
    }
    float h[DS];
#pragma unroll
    for (int n = 0; n < DS; ++n) h[n] = 0.f;

    unsigned short* xbase = xc + ((size_t)gd * TOK + (size_t)b * L_) * DI + ch0;
    const unsigned short* dbase = dtb + ((size_t)gd * TOK + (size_t)b * L_) * DI + ch0;
    const float* prb = proj + ((size_t)gd * TOK + (size_t)b * L_) * 64;

    for (int c = 0; c < 16; ++c) {
        const int a = dir ? (15 - c) : c;    // ascending chunk index
        const int t0 = a * 64;
        // ---- stage proj chunk ----
        if constexpr (PRE_DT) {
#pragma unroll
            for (int i = 0; i < 8; ++i) {
                int f = i * 64 + lane;       // 0..511 over [64 rows][8 f4]
                int row = f >> 3, c4 = f & 7;
                *(float4*)&prs[row * 32 + c4 * 4] =
                    *(const float4*)(prb + (size_t)(t0 + row) * 64 + 32 + c4 * 4);
            }
        } else {
#pragma unroll
            for (int i = 0; i < 16; ++i) {
                int f = i * 64 + lane;       // 0..1023 over [64 rows][16 f4]
                int row = f >> 4, c4 = f & 15;
                *(float4*)&prs[row * 64 + c4 * 4] =
                    *(const float4*)(prb + (size_t)(t0 + row) * 64 + c4 * 4);
            }
        }
        // ---- stage xc chunk (64 rows x 64 ch, bf16) ----
#pragma unroll
        for (int i = 0; i < 8; ++i) {
            int rr = i * 8 + (lane >> 3);
            int cc = (lane & 7) * 8;
            *(uint4*)&xcs[rr * 64 + cc] =
                *(const uint4*)(xbase + (size_t)(t0 + rr) * DI + cc);
        }
        if constexpr (PRE_DT) {
#pragma unroll
            for (int i = 0; i < 8; ++i) {
                int rr = i * 8 + (lane >> 3);
                int cc = (lane & 7) * 8;
                *(uint4*)&dts[rr * 64 + cc] =
                    *(const uint4*)(dbase + (size_t)(t0 + rr) * DI + cc);
            }
        }
        __syncthreads();
        // ---- sequential steps within chunk ----
        for (int s = 0; s < 64; ++s) {
            const int row = dir ? (63 - s) : s;
            float u = bf2f(xcs[row * 64 + lane]);
            float dtv;
            if constexpr (PRE_DT) {
                dtv = bf2f(dts[row * 64 + lane]);
            } else {
                float Pv[DTR];
                const float4* p4 = (const float4*)&prs[row * 64];
#pragma unroll
                for (int q = 0; q < 8; ++q) *(float4*)&Pv[q * 4] = p4[q];
                float a0 = bias;
#pragma unroll
                for (int k = 0; k < DTR; ++k) a0 += w[k] * Pv[k];
                dtv = fmaxf(a0, 0.f) + log1pf(__expf(-fabsf(a0)));
            }
            const float4* bc4 = PRE_DT ? (const float4*)&prs[row * 32]
                                       : (const float4*)&prs[row * 64 + 32];
            float Bv[16], Cv[16];
            *(float4*)&Bv[0]  = bc4[0]; *(float4*)&Bv[4]  = bc4[1];
            *(float4*)&Bv[8]  = bc4[2]; *(float4*)&Bv[12] = bc4[3];
            *(float4*)&Cv[0]  = bc4[4]; *(float4*)&Cv[4]  = bc4[5];
            *(float4*)&Cv[8]  = bc4[6]; *(float4*)&Cv[12] = bc4[7];
            float du = dtv * u;
            float acc = 0.f;
#pragma unroll
            for (int n = 0; n < DS; ++n) {
                float dA = __expf(dtv * An[n]);
                h[n] = dA * h[n] + du * Bv[n];
                acc += h[n] * Cv[n];
            }
            xbase[(size_t)(t0 + row) * DI + lane] = f2bf(acc + u * Dk);
        }
        __syncthreads();
    }
}

// ---------------- combine: ycomb = (yf+yb)*silu(z), in place over y_fwd slot ----------------
__global__ __launch_bounds__(256)
void k_combine(unsigned short* __restrict__ xcbuf, const unsigned short* __restrict__ xz)
{
    int g = blockIdx.y;
    size_t idx = ((size_t)blockIdx.x * 256 + threadIdx.x) * 4;   // m*DI + d
    size_t m = idx >> 10, d = idx & 1023;
    unsigned short* yf_p = xcbuf + (size_t)(2 * g) * TOK * DI + idx;
    const unsigned short* yb_p = xcbuf + (size_t)(2 * g + 1) * TOK * DI + idx;
    const unsigned short* z_p  = xz + ((size_t)g * TOK + m) * (2 * DI) + DI + d;
    ushort4 yf = *(const ushort4*)yf_p;
    ushort4 yb = *(const ushort4*)yb_p;
    ushort4 zz = *(const ushort4*)z_p;
    ushort4 o;
    o.x = f2bf((bf2f(yf.x) + bf2f(yb.x)) * silu_f(bf2f(zz.x)));
    o.y = f2bf((bf2f(yf.y) + bf2f(yb.y)) * silu_f(bf2f(zz.y)));
    o.z = f2bf((bf2f(yf.z) + bf2f(yb.z)) * silu_f(bf2f(zz.z)));
    o.w = f2bf((bf2f(yf.w) + bf2f(yb.w)) * silu_f(bf2f(zz.w)));
    *(ushort4*)yf_p = o;
}

// ---------------- out_proj: yo[g] = ycomb[g] @ out_proj_w[li]^T (f32 out) ----------------
__global__ __launch_bounds__(256)
void k_outproj(const unsigned short* __restrict__ xcbuf, const float* __restrict__ opw,
               float* __restrict__ yo, int layer)
{
    int g = blockIdx.z;
    int li = 2 * layer + (g >> 1);
    gemm_tile_nt<DM, DI, unsigned short, float>(
        xcbuf + (size_t)(2 * g) * TOK * DI,
        opw + (size_t)li * DM * DI,
        yo + (size_t)g * TOK * DM);
}

// ---------------- LayerNorm + residual + t-average ----------------
__device__ __forceinline__ void blk_red2(float& a, float& b, float* red)
{
#pragma unroll
    for (int o = 32; o; o >>= 1) {
        a += __shfl_down(a, o);
        b += __shfl_down(b, o);
    }
    int lane = threadIdx.x & 63, wid = threadIdx.x >> 6;
    if (lane == 0) { red[wid] = a; red[4 + wid] = b; }
    __syncthreads();
    a = red[0] + red[1] + red[2] + red[3];
    b = red[4] + red[5] + red[6] + red[7];
    __syncthreads();
}

__global__ __launch_bounds__(256)
void k_ln(const float* __restrict__ yo, const float* __restrict__ lnw,
          const float* __restrict__ lnb, const float* __restrict__ resA,
          const float* __restrict__ resT, const float* __restrict__ resV,
          float* __restrict__ outA, float* __restrict__ outT,
          float* __restrict__ outV, int layer)
{
    int tok = blockIdx.x, tid = threadIdx.x;
    __shared__ float red[8];
    float t1a = 0.f, t1b = 0.f;
#pragma unroll
    for (int s = 0; s < 4; ++s) {
        const float* p = yo + ((size_t)s * TOK + tok) * DM;
        float x0 = p[tid], x1 = p[tid + 256];
        float sm = x0 + x1, sq = x0 * x0 + x1 * x1;
        blk_red2(sm, sq, red);
        float mean = sm * (1.f / 512.f);
        float var  = sq * (1.f / 512.f) - mean * mean;
        float rstd = rsqrtf(var + 1e-6f);
        int li = 2 * layer + (s >> 1);
        int half = s & 1;
        const float* wv = lnw + (size_t)(li * 2 + half) * DM;
        const float* bv = lnb + (size_t)(li * 2 + half) * DM;
        float v0 = (x0 - mean) * rstd * wv[tid] + bv[tid];
        float v1 = (x1 - mean) * rstd * wv[tid + 256] + bv[tid + 256];
        size_t o0 = (size_t)tok * DM + tid, o1 = o0 + 256;
        if (s == 0) {
            outA[o0] = resA[o0] + v0;
            outA[o1] = resA[o1] + v1;
        } else if (s == 1) {
            t1a = v0; t1b = v1;
        } else if (s == 2) {
            outV[o0] = resV[o0] + v0;
            outV[o1] = resV[o1] + v1;
        } else {
            outT[o0] = resT[o0] + 0.5f * (t1a + v0);
            outT[o1] = resT[o1] + 0.5f * (t1b + v1);
        }
    }
}

extern "C" void kernel_launch(void* const* d_in, const int* in_sizes, int n_in,
                              void* d_out, int out_size, void* d_ws, size_t ws_size,
                              hipStream_t stream)
{
    (void)in_sizes; (void)n_in; (void)out_size;
    const float* a_x       = (const float*)d_in[0];
    const float* v_x       = (const float*)d_in[1];
    const float* t_x       = (const float*)d_in[2];
    const float* in_proj_w = (const float*)d_in[3];
    const float* conv_w    = (const float*)d_in[4];
    const float* conv_b    = (const float*)d_in[5];
    const float* xproj_w   = (const float*)d_in[6];
    const float* dtproj_w  = (const float*)d_in[7];
    const float* dtproj_b  = (const float*)d_in[8];
    const float* A_log     = (const float*)d_in[9];
    const float* Dskip     = (const float*)d_in[10];
    const float* out_proj_w= (const float*)d_in[11];
    const float* ln_w      = (const float*)d_in[12];
    const float* ln_b      = (const float*)d_in[13];

    char* wsb = (char*)d_ws;
    unsigned short* xz    = (unsigned short*)(wsb + XZB);
    unsigned short* xc    = (unsigned short*)(wsb + XCB);
    float*          proj  = (float*)(wsb + PRB);
    unsigned short* dtbuf = (unsigned short*)(wsb + DTB);
    float*          yo    = (float*)(wsb + XZB);   // overlays xz (dead after combine)

    const bool pre_dt = (ws_size >= WS_NEED_PRE);

    float* out   = (float*)d_out;
    float* slotA = out;
    float* slotV = out + (size_t)TOK * DM;
    float* slotT = out + (size_t)2 * TOK * DM;

    for (int layer = 0; layer < NLAYERS; ++layer) {
        const float* sa = layer ? slotA : a_x;
        const float* st = layer ? slotT : t_x;
        const float* sv = layer ? slotV : v_x;

        k_inproj <<<dim3(32, 64, 4),  256, 0, stream>>>(sa, st, sv, in_proj_w, xz, layer);
        k_conv   <<<dim3(4, 4096, 8), 256, 0, stream>>>(xz, conv_w, conv_b, xc, layer);
        k_xproj  <<<dim3(1, 64, 8),   256, 0, stream>>>(xc, xproj_w, proj, layer);
        if (pre_dt) {
            k_dtgemm<<<dim3(4, 64, 8), 256, 0, stream>>>(proj, dtproj_w, dtproj_b,
                                                         dtbuf, layer);
            k_scan2<true><<<dim3(16, 4, 8), 64, 0, stream>>>(xc, proj, dtbuf, dtproj_w,
                                                             dtproj_b, A_log, Dskip, layer);
        } else {
            k_scan2<false><<<dim3(16, 4, 8), 64, 0, stream>>>(xc, proj, dtbuf, dtproj_w,
                                                              dtproj_b, A_log, Dskip, layer);
        }
        k_combine<<<dim3(4096, 4),    256, 0, stream>>>(xc, xz);
        k_outproj<<<dim3(8, 64, 4),   256, 0, stream>>>(xc, out_proj_w, yo, layer);
        k_ln     <<<dim3(4096),       256, 0, stream>>>(yo, ln_w, ln_b, sa, st, sv,
                                                        slotA, slotT, slotV, layer);
    }
}

// Round 4
// 1748.212 us; speedup vs baseline: 2.1476x; 1.4911x over previous
//
#include <hip/hip_runtime.h>
#include <cstddef>

// Problem constants
constexpr int B_      = 4;
constexpr int L_      = 1024;
constexpr int DM      = 512;    // d_model
constexpr int DS      = 16;     // d_state
constexpr int DI      = 1024;   // d_inner
constexpr int DTR     = 32;     // dt_rank
constexpr int TOK     = B_ * L_;  // 4096 tokens
constexpr int NLAYERS = 2;

// ---- Workspace layout (BYTE offsets). Base = 142.6 MB (proven); +13.6 MB bf16 weights if ws allows. ----
// XZ : bf16 [4][TOK][2*DI]  (in_proj out; z live till combine; yo f32 overlays after)
// XC : bf16 [8][TOK][DI]    (conv out; scan writes y in-place; combine writes ycomb in-place)
// PR : f32  [8][TOK][64]    (xproj out: dt_r | B | C)
// WIB/WOB/WXB : bf16 weight copies (optional)
constexpr size_t XZB = 0;
constexpr size_t XCB = (size_t)4 * TOK * 2 * DI * 2;          //  67,108,864
constexpr size_t PRB = XCB + (size_t)8 * TOK * DI * 2;        // 134,217,728
constexpr size_t WIB = PRB + (size_t)8 * TOK * 64 * 4;        // 142,606,336
constexpr size_t WOB = WIB + (size_t)4 * 2 * DI * DM * 2;     // 150,994,944
constexpr size_t WXB = WOB + (size_t)4 * DM * DI * 2;         // 155,189,248
constexpr size_t WS_NEED_BF = WXB + (size_t)8 * 64 * DI * 2;  // 156,237,824

__device__ __forceinline__ float silu_f(float x) { return x / (1.f + __expf(-x)); }

__device__ __forceinline__ float bf2f(unsigned short u) {
    union { unsigned u; float f; } v; v.u = ((unsigned)u) << 16; return v.f;
}
__device__ __forceinline__ unsigned short f2bf(float f) {
    union { float f; unsigned u; } v; v.f = f;
    unsigned r = v.u + 0x7FFFu + ((v.u >> 16) & 1u);
    return (unsigned short)(r >> 16);
}

using bf16x8 = __attribute__((ext_vector_type(8))) short;
using f32x4v = __attribute__((ext_vector_type(4))) float;

// ---- stage 8 elements (as bf16) into LDS ----
__device__ __forceinline__ void stage8(unsigned short* dst, const float* src) {
    float4 v0 = *(const float4*)src;
    float4 v1 = *(const float4*)(src + 4);
    ushort4 o0, o1;
    o0.x = f2bf(v0.x); o0.y = f2bf(v0.y); o0.z = f2bf(v0.z); o0.w = f2bf(v0.w);
    o1.x = f2bf(v1.x); o1.y = f2bf(v1.y); o1.z = f2bf(v1.z); o1.w = f2bf(v1.w);
    *(ushort4*)dst = o0;
    *(ushort4*)(dst + 4) = o1;
}
__device__ __forceinline__ void stage8(unsigned short* dst, const unsigned short* src) {
    *(uint4*)dst = *(const uint4*)src;
}

// ---------------- MFMA GEMM: C[M,N] = A[M,K] @ W[N,K]^T ----------------
// 256 threads = 4 waves (WRxWC), each wave FMxFN fragments of 16x16, BK=32.
template<int N, int K, int BM, int BN, int FM, int FN, typename TA, typename TW, typename TC>
__device__ __forceinline__ void mfma_gemm(const TA* __restrict__ A,
                                          const TW* __restrict__ W,
                                          TC* __restrict__ C)
{
    constexpr int WC  = BN / (FN * 16);
    constexpr int LDA = 40;                       // bf16 per LDS row (32 + 8 pad)
    __shared__ unsigned short As[BM * LDA];
    __shared__ unsigned short Bs[BN * LDA];
    const int tid  = threadIdx.x;
    const int lane = tid & 63, wid = tid >> 6;
    const int wr = wid / WC, wc = wid % WC;
    const int row0 = blockIdx.y * BM, col0 = blockIdx.x * BN;

    f32x4v acc[FM][FN] = {};
    constexpr int AITER = BM * 4 / 256;           // 8-elem chunks per thread
    constexpr int BITER = BN * 4 / 256;

    for (int k0 = 0; k0 < K; k0 += 32) {
#pragma unroll
        for (int i = 0; i < AITER; ++i) {
            int f = i * 256 + tid;
            int row = f >> 2, c8 = (f & 3) * 8;
            stage8(&As[row * LDA + c8], A + (size_t)(row0 + row) * K + k0 + c8);
        }
#pragma unroll
        for (int i = 0; i < BITER; ++i) {
            int f = i * 256 + tid;
            int row = f >> 2, c8 = (f & 3) * 8;
            stage8(&Bs[row * LDA + c8], W + (size_t)(col0 + row) * K + k0 + c8);
        }
        __syncthreads();
        bf16x8 af[FM], bfr[FN];
#pragma unroll
        for (int m = 0; m < FM; ++m)
            af[m] = *(const bf16x8*)&As[(wr * FM * 16 + m * 16 + (lane & 15)) * LDA + (lane >> 4) * 8];
#pragma unroll
        for (int n = 0; n < FN; ++n)
            bfr[n] = *(const bf16x8*)&Bs[(wc * FN * 16 + n * 16 + (lane & 15)) * LDA + (lane >> 4) * 8];
#pragma unroll
        for (int m = 0; m < FM; ++m)
#pragma unroll
            for (int n = 0; n < FN; ++n)
                acc[m][n] = __builtin_amdgcn_mfma_f32_16x16x32_bf16(af[m], bfr[n], acc[m][n], 0, 0, 0);
        __syncthreads();
    }
#pragma unroll
    for (int m = 0; m < FM; ++m) {
#pragma unroll
        for (int n = 0; n < FN; ++n) {
            int r0 = row0 + wr * FM * 16 + m * 16 + (lane >> 4) * 4;
            int c  = col0 + wc * FN * 16 + n * 16 + (lane & 15);
#pragma unroll
            for (int v = 0; v < 4; ++v) {
                if constexpr (sizeof(TC) == 4)
                    C[(size_t)(r0 + v) * N + c] = acc[m][n][v];
                else
                    C[(size_t)(r0 + v) * N + c] = f2bf(acc[m][n][v]);
            }
        }
    }
}

// ---------------- weight cast f32 -> bf16 (once per launch, if ws allows) ----------------
__global__ __launch_bounds__(256)
void k_wcast(const float* __restrict__ w1, const float* __restrict__ w2,
             const float* __restrict__ w3, unsigned short* __restrict__ o1,
             unsigned short* __restrict__ o2, unsigned short* __restrict__ o3)
{
    constexpr int N1 = 4 * 2 * DI * DM;   // in_proj
    constexpr int N2 = 4 * DM * DI;       // out_proj
    constexpr int N3 = 8 * 64 * DI;       // xproj
    constexpr int T4 = (N1 + N2 + N3) / 4;
    for (int i = blockIdx.x * 256 + threadIdx.x; i < T4; i += gridDim.x * 256) {
        int e = i * 4;
        const float* src; unsigned short* dst; int off;
        if (e < N1)           { src = w1; dst = o1; off = e; }
        else if (e < N1 + N2) { src = w2; dst = o2; off = e - N1; }
        else                  { src = w3; dst = o3; off = e - N1 - N2; }
        float4 v = *(const float4*)(src + off);
        ushort4 o;
        o.x = f2bf(v.x); o.y = f2bf(v.y); o.z = f2bf(v.z); o.w = f2bf(v.w);
        *(ushort4*)(dst + off) = o;
    }
}

// ---------------- in_proj: xz[g] = src_g @ in_proj_w[li]^T (bf16 out) ----------------
// grid (16, 32, 4), block 256
template<typename TW>
__global__ __launch_bounds__(256)
void k_inproj(const float* __restrict__ pa, const float* __restrict__ pt,
              const float* __restrict__ pv, const TW* __restrict__ w_all,
              unsigned short* __restrict__ xz, int layer)
{
    int g = blockIdx.z;
    const float* A = (g == 0) ? pa : (g == 2) ? pv : pt;
    int li = 2 * layer + (g >> 1);
    mfma_gemm<2 * DI, DM, 128, 128, 4, 4, float, TW, unsigned short>(
        A, w_all + (size_t)li * (2 * DI) * DM, xz + (size_t)g * TOK * (2 * DI));
}

// ---------------- xproj: proj[gd] = xc[gd] @ xproj_w[li,dir]^T (f32 out) ----------------
// grid (1, 32, 8), block 256
template<typename TW>
__global__ __launch_bounds__(256)
void k_xproj(const unsigned short* __restrict__ xc, const TW* __restrict__ xpw,
             float* __restrict__ proj, int layer)
{
    int gd = blockIdx.z;
    int dir = gd & 1;
    int li = 2 * layer + (gd >> 2);
    mfma_gemm<64, DI, 128, 64, 4, 2, unsigned short, TW, float>(
        xc + (size_t)gd * TOK * DI,
        xpw + (size_t)(li * 2 + dir) * 64 * DI,
        proj + (size_t)gd * TOK * 64);
}

// ---------------- out_proj: yo[g] = ycomb[g] @ out_proj_w[li]^T (f32 out) ----------------
// grid (4, 32, 4), block 256
template<typename TW>
__global__ __launch_bounds__(256)
void k_outproj(const unsigned short* __restrict__ xcbuf, const TW* __restrict__ opw,
               float* __restrict__ yo, int layer)
{
    int g = blockIdx.z;
    int li = 2 * layer + (g >> 1);
    mfma_gemm<DM, DI, 128, 128, 4, 4, unsigned short, TW, float>(
        xcbuf + (size_t)(2 * g) * TOK * DI,
        opw + (size_t)li * DM * DI,
        yo + (size_t)g * TOK * DM);
}

// ---------------- causal/anticausal depthwise conv + SiLU (bf16 in/out, x4 vec) --------
// grid (4096, 8), block 256; thread handles 4 channels of one (token, gd)
__global__ __launch_bounds__(256)
void k_conv(const unsigned short* __restrict__ xz, const float* __restrict__ cw,
            const float* __restrict__ cb, unsigned short* __restrict__ xc, int layer)
{
    int mt = blockIdx.x;             // global token = b*1024 + t
    int gd = blockIdx.y;
    int g = gd >> 1, dir = gd & 1;
    int li = 2 * layer + (g >> 1);
    int d = threadIdx.x * 4;
    int wbase = (li * 2 + dir) * DI + d;
    float w[4][4];
    *(float4*)w[0] = *(const float4*)(cw + (size_t)(wbase + 0) * 4);
    *(float4*)w[1] = *(const float4*)(cw + (size_t)(wbase + 1) * 4);
    *(float4*)w[2] = *(const float4*)(cw + (size_t)(wbase + 2) * 4);
    *(float4*)w[3] = *(const float4*)(cw + (size_t)(wbase + 3) * 4);
    float4 bias = *(const float4*)(cb + wbase);
    float s0 = bias.x, s1 = bias.y, s2 = bias.z, s3 = bias.w;
    int b = mt >> 10, tt = mt & 1023;
    const unsigned short* xcol = xz + ((size_t)g * TOK + (size_t)(b << 10)) * (2 * DI) + d;
#pragma unroll
    for (int k = 0; k < 4; ++k) {
        int to = (dir == 0) ? (tt - 3 + k) : (tt + 3 - k);
        if (to >= 0 && to < L_) {                 // block-uniform branch
            ushort4 xv = *(const ushort4*)(xcol + (size_t)to * (2 * DI));
            s0 += w[0][k] * bf2f(xv.x);
            s1 += w[1][k] * bf2f(xv.y);
            s2 += w[2][k] * bf2f(xv.z);
            s3 += w[3][k] * bf2f(xv.w);
        }
    }
    ushort4 o;
    o.x = f2bf(silu_f(s0)); o.y = f2bf(silu_f(s1));
    o.z = f2bf(silu_f(s2)); o.w = f2bf(silu_f(s3));
    *(ushort4*)(xc + ((size_t)gd * TOK + mt) * DI + d) = o;
}

// ---------------- selective scan, chunked LDS staging, dt inline, y in place ----------
// grid (16, 4, 8), block 64 (one wave).
__global__ __launch_bounds__(64)
void k_scan2(unsigned short* __restrict__ xc, const float* __restrict__ proj,
             const float* __restrict__ dpw, const float* __restrict__ dpb,
             const float* __restrict__ A_log, const float* __restrict__ Dskip, int layer)
{
    __shared__ float prs[64 * 64];
    __shared__ unsigned short xcs[64 * 64];

    const int lane = threadIdx.x;
    const int gd = blockIdx.z, g = gd >> 1, dir = gd & 1;
    const int li = 2 * layer + (g >> 1);
    const int b = blockIdx.y;
    const int ch0 = blockIdx.x * 64;
    const int wl = (li * 2 + dir) * DI + ch0 + lane;

    float An[DS];
    const float* Ap = A_log + (size_t)wl * DS;
#pragma unroll
    for (int n = 0; n < DS; ++n) An[n] = -__expf(Ap[n]);
    const float Dk = Dskip[wl];
    float w[DTR];
    const float* wp = dpw + (size_t)wl * DTR;
#pragma unroll
    for (int k = 0; k < DTR; ++k) w[k] = wp[k];
    const float bias = dpb[wl];
    float h[DS];
#pragma unroll
    for (int n = 0; n < DS; ++n) h[n] = 0.f;

    unsigned short* xbase = xc + ((size_t)gd * TOK + (size_t)b * L_) * DI + ch0;
    const float* prb = proj + ((size_t)gd * TOK + (size_t)b * L_) * 64;

    for (int c = 0; c < 16; ++c) {
        const int a = dir ? (15 - c) : c;
        const int t0 = a * 64;
#pragma unroll
        for (int i = 0; i < 16; ++i) {
            int f = i * 64 + lane;           // [64 rows][16 float4]
            int row = f >> 4, c4 = f & 15;
            *(float4*)&prs[row * 64 + c4 * 4] =
                *(const float4*)(prb + (size_t)(t0 + row) * 64 + c4 * 4);
        }
#pragma unroll
        for (int i = 0; i < 8; ++i) {
            int rr = i * 8 + (lane >> 3);
            int cc = (lane & 7) * 8;
            *(uint4*)&xcs[rr * 64 + cc] =
                *(const uint4*)(xbase + (size_t)(t0 + rr) * DI + cc);
        }
        __syncthreads();
        for (int s = 0; s < 64; ++s) {
            const int row = dir ? (63 - s) : s;
            float u = bf2f(xcs[row * 64 + lane]);
            float Pv[DTR];
            const float4* p4 = (const float4*)&prs[row * 64];
#pragma unroll
            for (int q = 0; q < 8; ++q) *(float4*)&Pv[q * 4] = p4[q];
            float a0 = bias;
#pragma unroll
            for (int k = 0; k < DTR; ++k) a0 += w[k] * Pv[k];
            float dtv = fmaxf(a0, 0.f) + log1pf(__expf(-fabsf(a0)));
            float Bv[16], Cv[16];
            const float4* bc4 = (const float4*)&prs[row * 64 + 32];
            *(float4*)&Bv[0]  = bc4[0]; *(float4*)&Bv[4]  = bc4[1];
            *(float4*)&Bv[8]  = bc4[2]; *(float4*)&Bv[12] = bc4[3];
            *(float4*)&Cv[0]  = bc4[4]; *(float4*)&Cv[4]  = bc4[5];
            *(float4*)&Cv[8]  = bc4[6]; *(float4*)&Cv[12] = bc4[7];
            float du = dtv * u;
            float acc = 0.f;
#pragma unroll
            for (int n = 0; n < DS; ++n) {
                float dA = __expf(dtv * An[n]);
                h[n] = dA * h[n] + du * Bv[n];
                acc += h[n] * Cv[n];
            }
            xbase[(size_t)(t0 + row) * DI + lane] = f2bf(acc + u * Dk);
        }
        __syncthreads();
    }
}

// ---------------- combine: ycomb = (yf+yb)*silu(z), in place over y_fwd slot ----------
__global__ __launch_bounds__(256)
void k_combine(unsigned short* __restrict__ xcbuf, const unsigned short* __restrict__ xz)
{
    int g = blockIdx.y;
    size_t idx = ((size_t)blockIdx.x * 256 + threadIdx.x) * 4;   // m*DI + d
    size_t m = idx >> 10, d = idx & 1023;
    unsigned short* yf_p = xcbuf + (size_t)(2 * g) * TOK * DI + idx;
    const unsigned short* yb_p = xcbuf + (size_t)(2 * g + 1) * TOK * DI + idx;
    const unsigned short* z_p  = xz + ((size_t)g * TOK + m) * (2 * DI) + DI + d;
    ushort4 yf = *(const ushort4*)yf_p;
    ushort4 yb = *(const ushort4*)yb_p;
    ushort4 zz = *(const ushort4*)z_p;
    ushort4 o;
    o.x = f2bf((bf2f(yf.x) + bf2f(yb.x)) * silu_f(bf2f(zz.x)));
    o.y = f2bf((bf2f(yf.y) + bf2f(yb.y)) * silu_f(bf2f(zz.y)));
    o.z = f2bf((bf2f(yf.z) + bf2f(yb.z)) * silu_f(bf2f(zz.z)));
    o.w = f2bf((bf2f(yf.w) + bf2f(yb.w)) * silu_f(bf2f(zz.w)));
    *(ushort4*)yf_p = o;
}

// ---------------- LayerNorm + residual + t-average ----------------
__device__ __forceinline__ void blk_red2(float& a, float& b, float* red)
{
#pragma unroll
    for (int o = 32; o; o >>= 1) {
        a += __shfl_down(a, o);
        b += __shfl_down(b, o);
    }
    int lane = threadIdx.x & 63, wid = threadIdx.x >> 6;
    if (lane == 0) { red[wid] = a; red[4 + wid] = b; }
    __syncthreads();
    a = red[0] + red[1] + red[2] + red[3];
    b = red[4] + red[5] + red[6] + red[7];
    __syncthreads();
}

__global__ __launch_bounds__(256)
void k_ln(const float* __restrict__ yo, const float* __restrict__ lnw,
          const float* __restrict__ lnb, const float* __restrict__ resA,
          const float* __restrict__ resT, const float* __restrict__ resV,
          float* __restrict__ outA, float* __restrict__ outT,
          float* __restrict__ outV, int layer)
{
    int tok = blockIdx.x, tid = threadIdx.x;
    __shared__ float red[8];
    float t1a = 0.f, t1b = 0.f;
#pragma unroll
    for (int s = 0; s < 4; ++s) {
        const float* p = yo + ((size_t)s * TOK + tok) * DM;
        float x0 = p[tid], x1 = p[tid + 256];
        float sm = x0 + x1, sq = x0 * x0 + x1 * x1;
        blk_red2(sm, sq, red);
        float mean = sm * (1.f / 512.f);
        float var  = sq * (1.f / 512.f) - mean * mean;
        float rstd = rsqrtf(var + 1e-6f);
        int li = 2 * layer + (s >> 1);
        int half = s & 1;
        const float* wv = lnw + (size_t)(li * 2 + half) * DM;
        const float* bv = lnb + (size_t)(li * 2 + half) * DM;
        float v0 = (x0 - mean) * rstd * wv[tid] + bv[tid];
        float v1 = (x1 - mean) * rstd * wv[tid + 256] + bv[tid + 256];
        size_t o0 = (size_t)tok * DM + tid, o1 = o0 + 256;
        if (s == 0) {
            outA[o0] = resA[o0] + v0;
            outA[o1] = resA[o1] + v1;
        } else if (s == 1) {
            t1a = v0; t1b = v1;
        } else if (s == 2) {
            outV[o0] = resV[o0] + v0;
            outV[o1] = resV[o1] + v1;
        } else {
            outT[o0] = resT[o0] + 0.5f * (t1a + v0);
            outT[o1] = resT[o1] + 0.5f * (t1b + v1);
        }
    }
}

extern "C" void kernel_launch(void* const* d_in, const int* in_sizes, int n_in,
                              void* d_out, int out_size, void* d_ws, size_t ws_size,
                              hipStream_t stream)
{
    (void)in_sizes; (void)n_in; (void)out_size;
    const float* a_x       = (const float*)d_in[0];
    const float* v_x       = (const float*)d_in[1];
    const float* t_x       = (const float*)d_in[2];
    const float* in_proj_w = (const float*)d_in[3];
    const float* conv_w    = (const float*)d_in[4];
    const float* conv_b    = (const float*)d_in[5];
    const float* xproj_w   = (const float*)d_in[6];
    const float* dtproj_w  = (const float*)d_in[7];
    const float* dtproj_b  = (const float*)d_in[8];
    const float* A_log     = (const float*)d_in[9];
    const float* Dskip     = (const float*)d_in[10];
    const float* out_proj_w= (const float*)d_in[11];
    const float* ln_w      = (const float*)d_in[12];
    const float* ln_b      = (const float*)d_in[13];

    char* wsb = (char*)d_ws;
    unsigned short* xz   = (unsigned short*)(wsb + XZB);
    unsigned short* xc   = (unsigned short*)(wsb + XCB);
    float*          proj = (float*)(wsb + PRB);
    float*          yo   = (float*)(wsb + XZB);   // overlays xz (dead after combine)
    unsigned short* wib  = (unsigned short*)(wsb + WIB);
    unsigned short* wob  = (unsigned short*)(wsb + WOB);
    unsigned short* wxb  = (unsigned short*)(wsb + WXB);

    const bool wbf = (ws_size >= WS_NEED_BF);

    float* out   = (float*)d_out;
    float* slotA = out;
    float* slotV = out + (size_t)TOK * DM;
    float* slotT = out + (size_t)2 * TOK * DM;

    if (wbf)
        k_wcast<<<dim3(1024), 256, 0, stream>>>(in_proj_w, out_proj_w, xproj_w,
                                                wib, wob, wxb);

    for (int layer = 0; layer < NLAYERS; ++layer) {
        const float* sa = layer ? slotA : a_x;
        const float* st = layer ? slotT : t_x;
        const float* sv = layer ? slotV : v_x;

        if (wbf)
            k_inproj<unsigned short><<<dim3(16, 32, 4), 256, 0, stream>>>(
                sa, st, sv, wib, xz, layer);
        else
            k_inproj<float><<<dim3(16, 32, 4), 256, 0, stream>>>(
                sa, st, sv, in_proj_w, xz, layer);

        k_conv<<<dim3(4096, 8), 256, 0, stream>>>(xz, conv_w, conv_b, xc, layer);

        if (wbf)
            k_xproj<unsigned short><<<dim3(1, 32, 8), 256, 0, stream>>>(
                xc, wxb, proj, layer);
        else
            k_xproj<float><<<dim3(1, 32, 8), 256, 0, stream>>>(
                xc, xproj_w, proj, layer);

        k_scan2<<<dim3(16, 4, 8), 64, 0, stream>>>(xc, proj, dtproj_w, dtproj_b,
                                                   A_log, Dskip, layer);
        k_combine<<<dim3(4096, 4), 256, 0, stream>>>(xc, xz);

        if (wbf)
            k_outproj<unsigned short><<<dim3(4, 32, 4), 256, 0, stream>>>(
                xc, wob, yo, layer);
        else
            k_outproj<float><<<dim3(4, 32, 4), 256, 0, stream>>>(
                xc, out_proj_w, yo, layer);

        k_ln<<<dim3(4096), 256, 0, stream>>>(yo, ln_w, ln_b, sa, st, sv,
                                             slotA, slotT, slotV, layer);
    }
}